// Round 5
// baseline (236.484 us; speedup 1.0000x reference)
//
#include <hip/hip_runtime.h>
#include <hip/hip_bf16.h>

#define L 512
#define CS 256
#define CZ 128
#define LN_EPS 1e-5f

typedef _Float16 f16_t;
typedef f16_t f16x8 __attribute__((ext_vector_type(8)));
typedef float f32x4 __attribute__((ext_vector_type(4)));

// ---- Kernel PREP -----------------------------------------------------------
// Per-block (i = blockIdx.x): embed + LN -> s_out, u2 (CHUNK-MAJOR f16:
// u2[c>>3][i][c&7]), zrow = u@W1 + b, zcol = u@W2.
// Spare duties: blocks 0..127 build w3c (chunk-major W3^T f16), blocks
// 128..391 build tab[cp*66+rp] = Ecp[cp] + Erp[rp].
__global__ __launch_bounds__(256) void k_prep(
    const int* __restrict__ seq, const int* __restrict__ cid,
    const int* __restrict__ ridx,
    const float* __restrict__ Eaa, const float* __restrict__ Epos,
    const float* __restrict__ Ech, const float* __restrict__ lnw,
    const float* __restrict__ lnb, const float* __restrict__ Wp,
    const float* __restrict__ bp, const float* __restrict__ Ecp,
    const float* __restrict__ Erp,
    float* __restrict__ s_out, f16_t* __restrict__ u2,
    float* __restrict__ zrow, float* __restrict__ zcol,
    f16_t* __restrict__ w3c, float* __restrict__ tab)
{
    __shared__ float su[CS];
    __shared__ float red[8];
    const int i = blockIdx.x;
    const int c = threadIdx.x;

    if (i < 128) {
        w3c[(c >> 3) * (CZ * 8) + i * 8 + (c & 7)] = (f16_t)Wp[(2 * CS + c) * CZ + i];
    } else if (i < 128 + 264) {
        const int b2 = i - 128;
        if (c < CZ)
            tab[b2 * CZ + c] = Ecp[(b2 / 66) * CZ + c] + Erp[(b2 % 66) * CZ + c];
    }

    const int sq = seq[i], ri = ridx[i], ci = cid[i];
    const float v = Eaa[sq * CS + c] + Epos[ri * CS + c] + Ech[ci * CS + c];
    s_out[i * CS + c] = v;

    float s1 = v, s2 = v * v;
    #pragma unroll
    for (int o = 32; o > 0; o >>= 1) {
        s1 += __shfl_down(s1, o, 64);
        s2 += __shfl_down(s2, o, 64);
    }
    const int wv = c >> 6, lane = c & 63;
    if (lane == 0) { red[wv * 2] = s1; red[wv * 2 + 1] = s2; }
    __syncthreads();
    const float S  = red[0] + red[2] + red[4] + red[6];
    const float SS = red[1] + red[3] + red[5] + red[7];
    const float mu  = S * (1.0f / CS);
    const float var = SS * (1.0f / CS) - mu * mu;
    const float rs  = rsqrtf(var + LN_EPS);
    const float u   = (v - mu) * rs * lnw[c] + lnb[c];
    u2[(c >> 3) * (L * 8) + i * 8 + (c & 7)] = (f16_t)u;
    su[c] = u;
    __syncthreads();

    const int z = c & 127;
    const int half = c >> 7;  // 0 -> zrow(W1), 1 -> zcol(W2)
    const float* W = Wp + half * CS * CZ + z;
    float a0 = 0, a1 = 0, a2 = 0, a3 = 0;
    #pragma unroll 8
    for (int cc = 0; cc < CS; cc += 4) {
        a0 += su[cc + 0] * W[(cc + 0) * CZ];
        a1 += su[cc + 1] * W[(cc + 1) * CZ];
        a2 += su[cc + 2] * W[(cc + 2) * CZ];
        a3 += su[cc + 3] * W[(cc + 3) * CZ];
    }
    const float acc = (a0 + a1) + (a2 + a3);
    if (half) zcol[i * CZ + z] = acc;
    else      zrow[i * CZ + z] = acc + bp[z];
}

// ---- Kernel PAIR (v6: R0 structure + i-group-of-4 to cut uj re-reads) ------
// Decomposition fix: with fill+prep+other = 138.3us constant, the R0
// original pair was ~35us (best); v3/v4/v5 = 55/45/48. v4/v5's regression:
// in-loop L2 A-loads on the MFMA critical path. v6 returns to the R0
// structure (A-frags hoisted to 32 VGPR pre-loop, wave owns 16z x 32j x 8i,
// LDS layout measured conflict-free, 4 waves/SIMD) with ONE change:
// i's processed in 2 groups of 4 (was 4 groups of 2), so uj fragments are
// read once per group -> LDS traffic 128 -> 96 b128/wave (49K -> 37K
// cyc/CU vs the 52K-cyc store drain; LDS was as loaded as the store pipe).
// Register math forces the epilogue into the MFMA C-initializer here:
// post-add would hold 12 extra f32x4 live across a 64-MFMA chain (~140
// VGPR > 128 cap at (512,4)); C-init keeps ~115. acc starts as
// zrow+zcol+tab (f32 reorder << tolerance), stores are pure fire-and-forget.
__global__ __launch_bounds__(512, 4) void k_pair(
    const f16_t* __restrict__ u2, const f16_t* __restrict__ w3c,
    const float* __restrict__ zrow, const float* __restrict__ zcol,
    const float* __restrict__ tab,
    const int* __restrict__ cid, const int* __restrict__ ridx,
    float* __restrict__ zout)
{
    __shared__ f16_t lds[(1024 + 256) * 8];  // u_j tile (16KB) + u_i tile (4KB)
    f16x8* lj = (f16x8*)lds;
    f16x8* li = ((f16x8*)lds) + 1024;

    const int t = threadIdx.x;
    const int lane = t & 63, wave = t >> 6;
    const int m = lane & 15, q = lane >> 4;
    const int j0 = blockIdx.x * 32, i0 = blockIdx.y * 8;
    const int zseg = wave * 16;
    const int zq = zseg + q * 4;             // this lane's 4 z's

    const f16x8* pu = (const f16x8*)u2;      // [32 chunks][512 rows]
    const f16x8* pw = (const f16x8*)w3c;     // [32 chunks][128 z]

    // stage LDS tiles (contiguous src + dst; measured conflict-free)
    if (t < 256) li[t] = pu[(t >> 3) * L + i0 + (t & 7)];   // t = ch*8 + ii
    #pragma unroll
    for (int rep = 0; rep < 2; ++rep) {
        const int un = rep * 512 + t;                       // un = ch*32 + jj
        lj[un] = pu[(un >> 5) * L + j0 + (un & 31)];
    }

    // A fragments hoisted pre-loop (32 VGPR) — NO loads on the MFMA path
    f16x8 A[8];
    #pragma unroll
    for (int k32 = 0; k32 < 8; ++k32)
        A[k32] = pw[(k32 * 4 + q) * CZ + zseg + m];

    // per-lane j operands, hoisted once per wave
    const int ja = j0 + m, jb = j0 + 16 + m;
    const int cja = cid[ja], rja = ridx[ja];
    const int cjb = cid[jb], rjb = ridx[jb];
    const f32x4 ZCa = *(const f32x4*)&zcol[ja * CZ + zq];
    const f32x4 ZCb = *(const f32x4*)&zcol[jb * CZ + zq];

    __syncthreads();

    #pragma unroll 1   // rolled: one group's live set; group-0 stores drain
    for (int g = 0; g < 2; ++g) {            // under group-1's reads/MFMAs
        const int ibase = i0 + g * 4;

        // C-init: acc = zrow + zcol + tab (loads complete under chain start;
        // operands die immediately -> no pressure across the 64-MFMA chain)
        f32x4 acc[4][2];
        #pragma unroll
        for (int ii = 0; ii < 4; ++ii) {
            const int i = ibase + ii;
            const int ci = cid[i], ri = ridx[i];
            int d;
            d = ri - rja; d = d < -32 ? -32 : (d > 32 ? 32 : d);
            const int xa = ((ci * 2 + cja) * 66) + ((ci == cja) ? (d + 32) : 65);
            d = ri - rjb; d = d < -32 ? -32 : (d > 32 ? 32 : d);
            const int xb = ((ci * 2 + cjb) * 66) + ((ci == cjb) ? (d + 32) : 65);
            const f32x4 zr = *(const f32x4*)&zrow[i * CZ + zq];
            acc[ii][0] = zr + ZCa + *(const f32x4*)&tab[xa * CZ + zq];
            acc[ii][1] = zr + ZCb + *(const f32x4*)&tab[xb * CZ + zq];
        }

        #pragma unroll
        for (int k32 = 0; k32 < 8; ++k32) {
            const int cb = k32 * 4 + q;
            const f16x8 uja = lj[cb * 32 + m];        // read ONCE per group
            const f16x8 ujb = lj[cb * 32 + 16 + m];   // (was once per i-pair)
            #pragma unroll
            for (int ii = 0; ii < 4; ++ii) {
                const f16x8 ui = li[cb * 8 + g * 4 + ii];  // broadcast read
                acc[ii][0] = __builtin_amdgcn_mfma_f32_16x16x32_f16(
                    A[k32], ui * uja, acc[ii][0], 0, 0, 0);
                acc[ii][1] = __builtin_amdgcn_mfma_f32_16x16x32_f16(
                    A[k32], ui * ujb, acc[ii][1], 0, 0, 0);
            }
        }

        // pure store epilogue (fire-and-forget)
        #pragma unroll
        for (int ii = 0; ii < 4; ++ii) {
            const int i = ibase + ii;
            float* r = zout + ((size_t)i * L + ja) * CZ + zq;
            *(f32x4*)r = acc[ii][0];
            *(f32x4*)(r + 16 * CZ) = acc[ii][1];      // jb = ja + 16
        }
    }
}

extern "C" void kernel_launch(void* const* d_in, const int* in_sizes, int n_in,
                              void* d_out, int out_size, void* d_ws, size_t ws_size,
                              hipStream_t stream) {
    const int*   seq  = (const int*)d_in[0];
    const int*   cid  = (const int*)d_in[1];
    const int*   ridx = (const int*)d_in[2];
    const float* Eaa  = (const float*)d_in[3];
    const float* Epos = (const float*)d_in[4];
    const float* Ech  = (const float*)d_in[5];
    const float* Ecp  = (const float*)d_in[6];
    const float* Erp  = (const float*)d_in[7];
    const float* Wp   = (const float*)d_in[8];
    const float* bp   = (const float*)d_in[9];
    const float* lnw  = (const float*)d_in[10];
    const float* lnb  = (const float*)d_in[11];

    float* out   = (float*)d_out;
    float* s_out = out;
    float* zout  = out + L * CS;

    char* ws = (char*)d_ws;
    f16_t* u2   = (f16_t*)ws;                 // 256 KB, chunk-major
    f16_t* w3c  = (f16_t*)(ws + 262144);      // 64 KB, chunk-major
    float* zrow = (float*)(ws + 327680);      // 256 KB
    float* zcol = (float*)(ws + 589824);      // 256 KB
    float* tab  = (float*)(ws + 851968);      // 132 KB

    hipLaunchKernelGGL(k_prep, dim3(L), dim3(256), 0, stream,
                       seq, cid, ridx, Eaa, Epos, Ech, lnw, lnb, Wp, bp,
                       Ecp, Erp, s_out, u2, zrow, zcol, w3c, tab);
    hipLaunchKernelGGL(k_pair, dim3(16, 64), dim3(512), 0, stream,
                       u2, w3c, zrow, zcol, tab, cid, ridx, zout);
}

// Round 6
// 224.444 us; speedup vs baseline: 1.0536x; 1.0536x over previous
//
#include <hip/hip_runtime.h>
#include <hip/hip_bf16.h>

#define L 512
#define CS 256
#define CZ 128
#define LN_EPS 1e-5f

typedef _Float16 f16_t;
typedef f16_t f16x8 __attribute__((ext_vector_type(8)));
typedef float f32x4 __attribute__((ext_vector_type(4)));

// ---- Kernel PREP -----------------------------------------------------------
// Per-block (i = blockIdx.x): embed + LN -> s_out, u2 (CHUNK-MAJOR f16:
// u2[c>>3][i][c&7]), zrow = u@W1 + b, zcol = u@W2.
// Spare duties: blocks 0..127 build w3c (chunk-major W3^T f16), blocks
// 128..391 build tab[cp*66+rp] = Ecp[cp] + Erp[rp].
__global__ __launch_bounds__(256) void k_prep(
    const int* __restrict__ seq, const int* __restrict__ cid,
    const int* __restrict__ ridx,
    const float* __restrict__ Eaa, const float* __restrict__ Epos,
    const float* __restrict__ Ech, const float* __restrict__ lnw,
    const float* __restrict__ lnb, const float* __restrict__ Wp,
    const float* __restrict__ bp, const float* __restrict__ Ecp,
    const float* __restrict__ Erp,
    float* __restrict__ s_out, f16_t* __restrict__ u2,
    float* __restrict__ zrow, float* __restrict__ zcol,
    f16_t* __restrict__ w3c, float* __restrict__ tab)
{
    __shared__ float su[CS];
    __shared__ float red[8];
    const int i = blockIdx.x;
    const int c = threadIdx.x;

    if (i < 128) {
        w3c[(c >> 3) * (CZ * 8) + i * 8 + (c & 7)] = (f16_t)Wp[(2 * CS + c) * CZ + i];
    } else if (i < 128 + 264) {
        const int b2 = i - 128;
        if (c < CZ)
            tab[b2 * CZ + c] = Ecp[(b2 / 66) * CZ + c] + Erp[(b2 % 66) * CZ + c];
    }

    const int sq = seq[i], ri = ridx[i], ci = cid[i];
    const float v = Eaa[sq * CS + c] + Epos[ri * CS + c] + Ech[ci * CS + c];
    s_out[i * CS + c] = v;

    float s1 = v, s2 = v * v;
    #pragma unroll
    for (int o = 32; o > 0; o >>= 1) {
        s1 += __shfl_down(s1, o, 64);
        s2 += __shfl_down(s2, o, 64);
    }
    const int wv = c >> 6, lane = c & 63;
    if (lane == 0) { red[wv * 2] = s1; red[wv * 2 + 1] = s2; }
    __syncthreads();
    const float S  = red[0] + red[2] + red[4] + red[6];
    const float SS = red[1] + red[3] + red[5] + red[7];
    const float mu  = S * (1.0f / CS);
    const float var = SS * (1.0f / CS) - mu * mu;
    const float rs  = rsqrtf(var + LN_EPS);
    const float u   = (v - mu) * rs * lnw[c] + lnb[c];
    u2[(c >> 3) * (L * 8) + i * 8 + (c & 7)] = (f16_t)u;
    su[c] = u;
    __syncthreads();

    const int z = c & 127;
    const int half = c >> 7;  // 0 -> zrow(W1), 1 -> zcol(W2)
    const float* W = Wp + half * CS * CZ + z;
    float a0 = 0, a1 = 0, a2 = 0, a3 = 0;
    #pragma unroll 8
    for (int cc = 0; cc < CS; cc += 4) {
        a0 += su[cc + 0] * W[(cc + 0) * CZ];
        a1 += su[cc + 1] * W[(cc + 1) * CZ];
        a2 += su[cc + 2] * W[(cc + 2) * CZ];
        a3 += su[cc + 3] * W[(cc + 3) * CZ];
    }
    const float acc = (a0 + a1) + (a2 + a3);
    if (half) zcol[i * CZ + z] = acc;
    else      zrow[i * CZ + z] = acc + bp[z];
}

// ---- Kernel PAIR (v7: full-cache-line stores + hoisted A) ------------------
// v6 counters exposed the real pathology: zseg=wave*16 -> each wave writes
// only 64B of each 128B L2 line; partner-wave halves don't merge in time ->
// RMW: FETCH +134MB (line readback), WRITE 2.4x (318MB). v2 (zsg=(wave&3)*32,
// full-line ownership) measured WRITE_SIZE == 131072 KB EXACTLY with 2.9MB
// fetch. v7 combines the individually-proven pieces:
//   - wave = 32z x 16j x 8i (zsg=(wave&3)*32, jh=wave>>2): each wave's two
//     16B stores per (i,j) cover one full 128B line -> no RMW (v2-proven)
//   - A0/A1 hoisted pre-loop, 64 VGPR: zero L2 loads on the MFMA critical
//     path (v4/v5's in-loop A-loads were their regression; v6 proved the
//     hoist costs only ~32 extra VGPR)
//   - LDS staging, measured conflict-free layout
//   - i's in 4 pairs, 4 independent MFMA chains/pair (R0)
//   - C-init acc = zrow+zcol+tab (numerically proven v5/v6); next pair's
//     init loads issue between chain-end and stores (T14 pattern) so the
//     L2 latency hides under the store burst + next chain
// Live ~105 VGPR + 16 AGPR -> fits 128-cap at (512,4) = 4 waves/SIMD.
__global__ __launch_bounds__(512, 4) void k_pair(
    const f16_t* __restrict__ u2, const f16_t* __restrict__ w3c,
    const float* __restrict__ zrow, const float* __restrict__ zcol,
    const float* __restrict__ tab,
    const int* __restrict__ cid, const int* __restrict__ ridx,
    float* __restrict__ zout)
{
    __shared__ f16_t lds[(1024 + 256) * 8];  // u_j tile (16KB) + u_i tile (4KB)
    f16x8* lj = (f16x8*)lds;
    f16x8* li = ((f16x8*)lds) + 1024;

    const int t = threadIdx.x;
    const int lane = t & 63, wave = t >> 6;
    const int m = lane & 15, q = lane >> 4;
    const int j0 = blockIdx.x * 32, i0 = blockIdx.y * 8;
    const int zsg = (wave & 3) * 32;      // full 128B-line z ownership
    const int jh = wave >> 2;             // 16 j's per wave
    const int jm = j0 + jh * 16 + m;
    const int zq0 = zsg + q * 4;          // line half 0
    const int zq1 = zsg + 16 + q * 4;     // line half 1 (same 128B line)

    const f16x8* pu = (const f16x8*)u2;   // [32 chunks][512 rows]
    const f16x8* pw = (const f16x8*)w3c;  // [32 chunks][128 z]

    // stage LDS tiles (contiguous src + dst; measured conflict-free)
    if (t < 256) li[t] = pu[(t >> 3) * L + i0 + (t & 7)];   // t = ch*8 + ii
    #pragma unroll
    for (int rep = 0; rep < 2; ++rep) {
        const int un = rep * 512 + t;                       // un = ch*32 + jj
        lj[un] = pu[(un >> 5) * L + j0 + (un & 31)];
    }

    // A fragments hoisted pre-loop (64 VGPR) — NO loads on the MFMA path
    f16x8 A0[8], A1[8];
    #pragma unroll
    for (int k32 = 0; k32 < 8; ++k32) {
        A0[k32] = pw[(k32 * 4 + q) * CZ + zsg + m];
        A1[k32] = pw[(k32 * 4 + q) * CZ + zsg + 16 + m];
    }

    // per-wave j operands
    const int cj = cid[jm], rj = ridx[jm];
    const f32x4 ZC0 = *(const f32x4*)&zcol[jm * CZ + zq0];
    const f32x4 ZC1 = *(const f32x4*)&zcol[jm * CZ + zq1];

    // C-init helper: acc = zrow + zcol + tab for row i
    auto cinit = [&](int i, f32x4& c0, f32x4& c1) {
        const int ci = cid[i], ri = ridx[i];
        int d = ri - rj; d = d < -32 ? -32 : (d > 32 ? 32 : d);
        const int x = ((ci * 2 + cj) * 66) + ((ci == cj) ? (d + 32) : 65);
        c0 = *(const f32x4*)&zrow[i * CZ + zq0] + ZC0
           + *(const f32x4*)&tab[x * CZ + zq0];
        c1 = *(const f32x4*)&zrow[i * CZ + zq1] + ZC1
           + *(const f32x4*)&tab[x * CZ + zq1];
    };

    // prologue: pair-0 C-init issues pre-barrier (hides under staging drain)
    f32x4 c00, c01, c10, c11;
    cinit(i0, c00, c01);
    cinit(i0 + 1, c10, c11);

    __syncthreads();

    #pragma unroll 1   // rolled: pins regs; stores of pair g drain under g+1
    for (int ig = 0; ig < 4; ++ig) {
        f32x4 a00 = c00, a01 = c01, a10 = c10, a11 = c11;

        #pragma unroll
        for (int k32 = 0; k32 < 8; ++k32) {
            const int cb = k32 * 4 + q;
            const f16x8 uj = lj[cb * 32 + jh * 16 + m];      // conflict-free
            const f16x8 B0 = li[cb * 8 + ig * 2] * uj;       // bcast + 4 v_pk
            const f16x8 B1 = li[cb * 8 + ig * 2 + 1] * uj;
            a00 = __builtin_amdgcn_mfma_f32_16x16x32_f16(A0[k32], B0, a00, 0, 0, 0);
            a01 = __builtin_amdgcn_mfma_f32_16x16x32_f16(A1[k32], B0, a01, 0, 0, 0);
            a10 = __builtin_amdgcn_mfma_f32_16x16x32_f16(A0[k32], B1, a10, 0, 0, 0);
            a11 = __builtin_amdgcn_mfma_f32_16x16x32_f16(A1[k32], B1, a11, 0, 0, 0);
        }

        // next pair's C-init loads: issue BEFORE stores so L2 latency hides
        // under the store burst + next chain start
        if (ig < 3) {
            cinit(i0 + ig * 2 + 2, c00, c01);
            cinit(i0 + ig * 2 + 3, c10, c11);
        }

        // stores: two 16B per (i, jm) covering one FULL 128B line -> merge
        float* r0 = zout + ((size_t)(i0 + ig * 2) * L + jm) * CZ;
        float* r1 = r0 + (size_t)L * CZ;
        *(f32x4*)(r0 + zq0) = a00;
        *(f32x4*)(r0 + zq1) = a01;
        *(f32x4*)(r1 + zq0) = a10;
        *(f32x4*)(r1 + zq1) = a11;
    }
}

extern "C" void kernel_launch(void* const* d_in, const int* in_sizes, int n_in,
                              void* d_out, int out_size, void* d_ws, size_t ws_size,
                              hipStream_t stream) {
    const int*   seq  = (const int*)d_in[0];
    const int*   cid  = (const int*)d_in[1];
    const int*   ridx = (const int*)d_in[2];
    const float* Eaa  = (const float*)d_in[3];
    const float* Epos = (const float*)d_in[4];
    const float* Ech  = (const float*)d_in[5];
    const float* Ecp  = (const float*)d_in[6];
    const float* Erp  = (const float*)d_in[7];
    const float* Wp   = (const float*)d_in[8];
    const float* bp   = (const float*)d_in[9];
    const float* lnw  = (const float*)d_in[10];
    const float* lnb  = (const float*)d_in[11];

    float* out   = (float*)d_out;
    float* s_out = out;
    float* zout  = out + L * CS;

    char* ws = (char*)d_ws;
    f16_t* u2   = (f16_t*)ws;                 // 256 KB, chunk-major
    f16_t* w3c  = (f16_t*)(ws + 262144);      // 64 KB, chunk-major
    float* zrow = (float*)(ws + 327680);      // 256 KB
    float* zcol = (float*)(ws + 589824);      // 256 KB
    float* tab  = (float*)(ws + 851968);      // 132 KB

    hipLaunchKernelGGL(k_prep, dim3(L), dim3(256), 0, stream,
                       seq, cid, ridx, Eaa, Epos, Ech, lnw, lnb, Wp, bp,
                       Ecp, Erp, s_out, u2, zrow, zcol, w3c, tab);
    hipLaunchKernelGGL(k_pair, dim3(16, 64), dim3(512), 0, stream,
                       u2, w3c, zrow, zcol, tab, cid, ridx, zout);
}

// Round 7
// 197.724 us; speedup vs baseline: 1.1960x; 1.1351x over previous
//
#include <hip/hip_runtime.h>
#include <hip/hip_bf16.h>

#define L 512
#define CS 256
#define CZ 128
#define LN_EPS 1e-5f

typedef _Float16 f16_t;
typedef f16_t f16x8 __attribute__((ext_vector_type(8)));
typedef float f32x4 __attribute__((ext_vector_type(4)));

#define PIN4(x) asm volatile("" : "+v"(reinterpret_cast<f32x4&>(x)))

// ---- Kernel PREP -----------------------------------------------------------
// Per-block (i = blockIdx.x): embed + LN -> s_out, u2 (CHUNK-MAJOR f16:
// u2[c>>3][i][c&7]), zrow = u@W1 + b, zcol = u@W2.
// Spare duties: blocks 0..127 build w3c (chunk-major W3^T f16), blocks
// 128..391 build tab[cp*66+rp] = Ecp[cp] + Erp[rp].
__global__ __launch_bounds__(256) void k_prep(
    const int* __restrict__ seq, const int* __restrict__ cid,
    const int* __restrict__ ridx,
    const float* __restrict__ Eaa, const float* __restrict__ Epos,
    const float* __restrict__ Ech, const float* __restrict__ lnw,
    const float* __restrict__ lnb, const float* __restrict__ Wp,
    const float* __restrict__ bp, const float* __restrict__ Ecp,
    const float* __restrict__ Erp,
    float* __restrict__ s_out, f16_t* __restrict__ u2,
    float* __restrict__ zrow, float* __restrict__ zcol,
    f16_t* __restrict__ w3c, float* __restrict__ tab)
{
    __shared__ float su[CS];
    __shared__ float red[8];
    const int i = blockIdx.x;
    const int c = threadIdx.x;

    if (i < 128) {
        w3c[(c >> 3) * (CZ * 8) + i * 8 + (c & 7)] = (f16_t)Wp[(2 * CS + c) * CZ + i];
    } else if (i < 128 + 264) {
        const int b2 = i - 128;
        if (c < CZ)
            tab[b2 * CZ + c] = Ecp[(b2 / 66) * CZ + c] + Erp[(b2 % 66) * CZ + c];
    }

    const int sq = seq[i], ri = ridx[i], ci = cid[i];
    const float v = Eaa[sq * CS + c] + Epos[ri * CS + c] + Ech[ci * CS + c];
    s_out[i * CS + c] = v;

    float s1 = v, s2 = v * v;
    #pragma unroll
    for (int o = 32; o > 0; o >>= 1) {
        s1 += __shfl_down(s1, o, 64);
        s2 += __shfl_down(s2, o, 64);
    }
    const int wv = c >> 6, lane = c & 63;
    if (lane == 0) { red[wv * 2] = s1; red[wv * 2 + 1] = s2; }
    __syncthreads();
    const float S  = red[0] + red[2] + red[4] + red[6];
    const float SS = red[1] + red[3] + red[5] + red[7];
    const float mu  = S * (1.0f / CS);
    const float var = SS * (1.0f / CS) - mu * mu;
    const float rs  = rsqrtf(var + LN_EPS);
    const float u   = (v - mu) * rs * lnw[c] + lnb[c];
    u2[(c >> 3) * (L * 8) + i * 8 + (c & 7)] = (f16_t)u;
    su[c] = u;
    __syncthreads();

    const int z = c & 127;
    const int half = c >> 7;  // 0 -> zrow(W1), 1 -> zcol(W2)
    const float* W = Wp + half * CS * CZ + z;
    float a0 = 0, a1 = 0, a2 = 0, a3 = 0;
    #pragma unroll 8
    for (int cc = 0; cc < CS; cc += 4) {
        a0 += su[cc + 0] * W[(cc + 0) * CZ];
        a1 += su[cc + 1] * W[(cc + 1) * CZ];
        a2 += su[cc + 2] * W[(cc + 2) * CZ];
        a3 += su[cc + 3] * W[(cc + 3) * CZ];
    }
    const float acc = (a0 + a1) + (a2 + a3);
    if (half) zcol[i * CZ + z] = acc;
    else      zrow[i * CZ + z] = acc + bp[z];
}

// ---- Kernel PAIR (v8: 1 block/CU, small dirty footprint, zero LDS) ---------
// Traffic forensics across rounds: v2 (exact WRITE=131072KB, FETCH=2.9MB)
// ran with ~64KB output region and low co-residency; v6/v7 (WRITE 2.4x/1.45x,
// FETCH ~0.8-1.1x output) ran 2 blocks/CU x 128KB region = ~8MB dirty lines
// per 4MB XCD-L2 -> half-written 128B lines evicted between 64B sector
// writes -> RMW readback + double write. Controlling variable = dirty
// footprint vs L2, NOT the store instruction pattern.
// v8: grid = 256 blocks (1/CU guaranteed), each loops 8 jobs of 16j x 8i.
// Active region <= 64KB/block -> 2MB/XCD << 4MB L2 -> lines merge + drain.
//   - wave = 32z x 16j x 4i; zsg=(wave&3)*32 owns full 128B lines (v2-proven)
//   - zero LDS, zero barriers: UJ[8] per-lane j-fragments (regs, per job),
//     A0/A1[8] job-invariant (regs, once), u_i = 64-lane-broadcast L2 loads
//     in the unrolled chain (16/burst, scheduler-prefetchable)
//   - all hoists pinned with empty asm so the allocator can't re-sink them
//     (v2's VGPR=76 sink failure)
//   - C-init acc = zrow+zcol+tab (proven v5-v7), burst-ahead prefetch
// Compute ~8K cyc/CU vs 52K-cyc store floor -> store-bound even at 8
// waves/CU. VGPR target 150-200 (fits (512,2) cap 256, no spill).
__global__ __launch_bounds__(512, 2) void k_pair(
    const f16_t* __restrict__ u2, const f16_t* __restrict__ w3c,
    const float* __restrict__ zrow, const float* __restrict__ zcol,
    const float* __restrict__ tab,
    const int* __restrict__ cid, const int* __restrict__ ridx,
    float* __restrict__ zout)
{
    const int t = threadIdx.x;
    const int lane = t & 63, wave = t >> 6;
    const int m = lane & 15, q = lane >> 4;
    const int zsg = (wave & 3) * 32;      // full 128B-line z ownership
    const int ih  = wave >> 2;            // 0/1: which 4-i half of the tile
    const int zq0 = zsg + q * 4;          // line half 0
    const int zq1 = zsg + 16 + q * 4;     // line half 1 (same 128B line)

    const f16x8* pu = (const f16x8*)u2;   // [32 chunks][512 rows]
    const f16x8* pw = (const f16x8*)w3c;  // [32 chunks][128 z]

    // job-invariant A fragments (64 VGPR), loaded once and pinned
    f16x8 A0[8], A1[8];
    #pragma unroll
    for (int k = 0; k < 8; ++k) {
        A0[k] = pw[(k * 4 + q) * CZ + zsg + m];
        A1[k] = pw[(k * 4 + q) * CZ + zsg + 16 + m];
    }
    #pragma unroll
    for (int k = 0; k < 8; ++k) { PIN4(A0[k]); PIN4(A1[k]); }

    const int b = blockIdx.x;
    const int it2 = b >> 3;               // [0,32): pair of i-tiles
    const int jt8 = b & 7;                // [0,8):  quad of j-tiles

    #pragma unroll 1
    for (int r = 0; r < 8; ++r) {
        const int jt = jt8 * 4 + (r & 3);     // [0,32)
        const int it = it2 * 2 + (r >> 2);    // [0,64)
        const int j0 = jt * 16, i0 = it * 8;
        const int jm = j0 + m;
        const int ibase = i0 + ih * 4;        // this wave's 4 i's

        // per-job j-side operands: u_j fragments into registers, pinned
        f16x8 UJ[8];
        #pragma unroll
        for (int k = 0; k < 8; ++k)
            UJ[k] = pu[(k * 4 + q) * L + jm];
        #pragma unroll
        for (int k = 0; k < 8; ++k) PIN4(UJ[k]);

        const int cj = cid[jm], rj = ridx[jm];
        const f32x4 ZC0 = *(const f32x4*)&zcol[jm * CZ + zq0];
        const f32x4 ZC1 = *(const f32x4*)&zcol[jm * CZ + zq1];

        auto cinit = [&](int i, f32x4& c0, f32x4& c1) {
            const int ci = cid[i], ri = ridx[i];
            int d = ri - rj; d = d < -32 ? -32 : (d > 32 ? 32 : d);
            const int x = ((ci * 2 + cj) * 66) + ((ci == cj) ? (d + 32) : 65);
            c0 = *(const f32x4*)&zrow[i * CZ + zq0] + ZC0
               + *(const f32x4*)&tab[x * CZ + zq0];
            c1 = *(const f32x4*)&zrow[i * CZ + zq1] + ZC1
               + *(const f32x4*)&tab[x * CZ + zq1];
        };

        f32x4 c00, c01, c10, c11;
        cinit(ibase,     c00, c01);
        cinit(ibase + 1, c10, c11);

        #pragma unroll 1   // rolled: burst-0 stores drain under burst-1
        for (int ig = 0; ig < 2; ++ig) {
            const int ia = ibase + ig * 2;
            f32x4 a00 = c00, a01 = c01, a10 = c10, a11 = c11;

            #pragma unroll
            for (int k = 0; k < 8; ++k) {
                const int cb = k * 4 + q;
                const f16x8 ui0 = pu[cb * L + ia];       // 64-lane broadcast
                const f16x8 ui1 = pu[cb * L + ia + 1];   // L2-resident
                const f16x8 B0 = ui0 * UJ[k];
                const f16x8 B1 = ui1 * UJ[k];
                a00 = __builtin_amdgcn_mfma_f32_16x16x32_f16(A0[k], B0, a00, 0, 0, 0);
                a01 = __builtin_amdgcn_mfma_f32_16x16x32_f16(A1[k], B0, a01, 0, 0, 0);
                a10 = __builtin_amdgcn_mfma_f32_16x16x32_f16(A0[k], B1, a10, 0, 0, 0);
                a11 = __builtin_amdgcn_mfma_f32_16x16x32_f16(A1[k], B1, a11, 0, 0, 0);
            }

            // next burst's C-init: issues before stores, hides under them
            if (ig == 0) {
                cinit(ibase + 2, c00, c01);
                cinit(ibase + 3, c10, c11);
            }

            // stores: this wave covers one FULL 128B line per (i, jm)
            float* r0 = zout + ((size_t)ia * L + jm) * CZ;
            float* r1 = r0 + (size_t)L * CZ;
            *(f32x4*)(r0 + zq0) = a00;
            *(f32x4*)(r0 + zq1) = a01;
            *(f32x4*)(r1 + zq0) = a10;
            *(f32x4*)(r1 + zq1) = a11;
        }
    }
}

extern "C" void kernel_launch(void* const* d_in, const int* in_sizes, int n_in,
                              void* d_out, int out_size, void* d_ws, size_t ws_size,
                              hipStream_t stream) {
    const int*   seq  = (const int*)d_in[0];
    const int*   cid  = (const int*)d_in[1];
    const int*   ridx = (const int*)d_in[2];
    const float* Eaa  = (const float*)d_in[3];
    const float* Epos = (const float*)d_in[4];
    const float* Ech  = (const float*)d_in[5];
    const float* Ecp  = (const float*)d_in[6];
    const float* Erp  = (const float*)d_in[7];
    const float* Wp   = (const float*)d_in[8];
    const float* bp   = (const float*)d_in[9];
    const float* lnw  = (const float*)d_in[10];
    const float* lnb  = (const float*)d_in[11];

    float* out   = (float*)d_out;
    float* s_out = out;
    float* zout  = out + L * CS;

    char* ws = (char*)d_ws;
    f16_t* u2   = (f16_t*)ws;                 // 256 KB, chunk-major
    f16_t* w3c  = (f16_t*)(ws + 262144);      // 64 KB, chunk-major
    float* zrow = (float*)(ws + 327680);      // 256 KB
    float* zcol = (float*)(ws + 589824);      // 256 KB
    float* tab  = (float*)(ws + 851968);      // 132 KB

    hipLaunchKernelGGL(k_prep, dim3(L), dim3(256), 0, stream,
                       seq, cid, ridx, Eaa, Epos, Ech, lnw, lnb, Wp, bp,
                       Ecp, Erp, s_out, u2, zrow, zcol, w3c, tab);
    hipLaunchKernelGGL(k_pair, dim3(256), dim3(512), 0, stream,
                       u2, w3c, zrow, zcol, tab, cid, ridx, zout);
}